// Round 2
// baseline (111.907 us; speedup 1.0000x reference)
//
#include <hip/hip_runtime.h>

// Problem constants (from reference): N=128 nodes, H=2 heads, L=1024.
#define NN 128
#define HH 2
#define LL 1024
#define NH (NN * HH)          // 256 rows
#define NHL (NN * HH * LL)    // 262144 elements per (n,h,l) tensor
#define COLS (HH * LL)        // 2048 columns of the alpha matrix
#define MAGIC 0x5EEDBA5Eu     // barrier flag value (xor'd with block id)

// Fused kernel, single REGULAR launch (graph-capturable, unlike
// hipLaunchCooperativeKernel which cost +36us in round 1).
// Phase 1 = per-(n,h) row scan (relu, cumsum -> Ss, decay recurrence -> Is
// -> alpha). Phase 2 = node-mix matvec + pred.
// Grid barrier is hand-rolled: per-block flags written with MAGIC^bid
// (robust to workspace re-poison: no zero-init assumption), agent-scope
// release/acquire atomics + __threadfence for cross-XCD visibility.
// All 256 blocks (4 waves each, tiny LDS/VGPR) are trivially co-resident
// on 256 CUs, so the spin cannot deadlock.
__global__ __launch_bounds__(256) void fused_kernel(
    const float* __restrict__ x, const float* __restrict__ Amat,
    const float* __restrict__ taus, const float* __restrict__ r0d,
    float* __restrict__ out_pred, float* __restrict__ out_signal,
    float* __restrict__ out_tmatT, float* __restrict__ ws_alpha,
    float* __restrict__ ws_ss, unsigned* __restrict__ flags) {
  const int bid = blockIdx.x;
  const int tid = threadIdx.x;

  // ---------------- Phase 1: row scan (row = bid) ----------------
  {
    const int row = bid;  // n*H + h
    const int lane = tid & 63;
    const int wave = tid >> 6;

    const float4* xr = (const float4*)(x + (size_t)row * LL);
    float4 v = xr[tid];
    float s0 = fmaxf(v.x, 0.f);
    float s1 = fmaxf(v.y, 0.f);
    float s2 = fmaxf(v.z, 0.f);
    float s3 = fmaxf(v.w, 0.f);

    const float tau = taus[row];
    const float d = 1.f - 1.f / tau;  // == exp(log(1 - 1/tau))
    const float R0 = r0d[row];

    // thread-local inclusive prefix sums (chunk of 4)
    float c0 = s0, c1 = c0 + s1, c2 = c1 + s2, c3 = c2 + s3;
    // thread-local decay recurrence (zero incoming state)
    float l0 = s0;
    float l1 = fmaf(d, l0, s1);
    float l2 = fmaf(d, l1, s2);
    float l3 = fmaf(d, l2, s3);

    // in-wave weighted inclusive scan over (chunk sum, chunk-end state)
    float vs = c3;
    float vi = l3;
    float D = d * d;
    D = D * D;     // d^4
    float Dp = D;  // D^off
#pragma unroll
    for (int off = 1; off < 64; off <<= 1) {
      float ps = __shfl_up(vs, off);
      float pi = __shfl_up(vi, off);
      if (lane >= off) {
        vs += ps;
        vi = fmaf(Dp, pi, vi);
      }
      Dp *= Dp;
    }
    // Dp == D^64 == wave ratio W

    __shared__ float tw_s[4];
    __shared__ float tw_i[4];
    if (lane == 63) {
      tw_s[wave] = vs;
      tw_i[wave] = vi;
    }
    __syncthreads();

    // wave-incoming totals (sequential combine over earlier waves)
    float S_in = 0.f, I_in = 0.f;
    for (int u = 0; u < wave; ++u) {
      S_in += tw_s[u];
      I_in = fmaf(I_in, Dp, tw_i[u]);  // I = I*W + I_u
    }

    // per-lane exclusive (state at end of previous chunk, within wave)
    float es = __shfl_up(vs, 1);
    float ei = __shfl_up(vi, 1);
    if (lane == 0) {
      es = 0.f;
      ei = 0.f;
    }
    const float exs = S_in + es;
    // wave-incoming state decays D^lane before reaching this chunk
    const float state = fmaf(I_in, exp2f((float)lane * log2f(D)), ei);

    // finalize per element
    float cum0 = exs + c0, cum1 = exs + c1, cum2 = exs + c2, cum3 = exs + c3;
    float is0 = fmaf(d, state, s0);
    float is1 = fmaf(d, is0, s1);
    float is2 = fmaf(d, is1, s2);
    float is3 = fmaf(d, is2, s3);

    float4 sig = make_float4(s0, s1, s2, s3);
    float4 ss = make_float4(1.f - cum0, 1.f - cum1, 1.f - cum2, 1.f - cum3);
    float4 al = make_float4(1.f - __expf(-R0 * is0), 1.f - __expf(-R0 * is1),
                            1.f - __expf(-R0 * is2), 1.f - __expf(-R0 * is3));

    const size_t base = (size_t)row * LL / 4 + tid;
    ((float4*)(out_signal))[base] = sig;  // output 1: signal
    ((float4*)(ws_alpha))[base] = al;
    ((float4*)(ws_ss))[base] = ss;
  }

  // tmatT = Amat + I (16384 elements; first 4096 flat threads, float4 each).
  {
    const int fid = bid * 256 + tid;
    if (fid < NN * NN / 4) {
      float4 t = ((const float4*)Amat)[fid];
      const int e = fid << 2;
      if (((e + 0) % (NN + 1)) == 0) t.x += 1.f;
      if (((e + 1) % (NN + 1)) == 0) t.y += 1.f;
      if (((e + 2) % (NN + 1)) == 0) t.z += 1.f;
      if (((e + 3) % (NN + 1)) == 0) t.w += 1.f;
      ((float4*)out_tmatT)[fid] = t;
    }
  }

  // ---------------- Manual grid barrier ----------------
  // Make this block's ws writes agent-visible, then publish flag.
  __threadfence();   // agent-scope release of phase-1 stores
  __syncthreads();   // all threads' stores+fences complete
  if (tid == 0) {
    __hip_atomic_store(&flags[bid], MAGIC ^ (unsigned)bid, __ATOMIC_RELEASE,
                       __HIP_MEMORY_SCOPE_AGENT);
  }
  // thread t polls flag t: block proceeds only when all 256 flags are set
  while (__hip_atomic_load(&flags[tid], __ATOMIC_RELAXED,
                           __HIP_MEMORY_SCOPE_AGENT) !=
         (MAGIC ^ (unsigned)tid)) {
    __builtin_amdgcn_s_sleep(2);
  }
  __syncthreads();
  __threadfence();   // agent-scope acquire: invalidate stale cache lines

  // ---------------- Phase 2: mix ----------------
  {
    const int rg = bid >> 3;                                 // 32 rowgroups
    const int cg_ = bid & 7;                                 // 8 colgroups
    const int col = (cg_ << 8) + tid;                        // 0..2047
    const int k0 = __builtin_amdgcn_readfirstlane(rg << 2);  // block-uniform

    const float* __restrict__ a0 = Amat + (k0 + 0) * NN;
    const float* __restrict__ a1 = Amat + (k0 + 1) * NN;
    const float* __restrict__ a2 = Amat + (k0 + 2) * NN;
    const float* __restrict__ a3 = Amat + (k0 + 3) * NN;

    // +I term
    float acc0 = ws_alpha[(size_t)(k0 + 0) * COLS + col];
    float acc1 = ws_alpha[(size_t)(k0 + 1) * COLS + col];
    float acc2 = ws_alpha[(size_t)(k0 + 2) * COLS + col];
    float acc3 = ws_alpha[(size_t)(k0 + 3) * COLS + col];

    const float* __restrict__ ac = ws_alpha + col;
#pragma unroll 8
    for (int m = 0; m < NN; ++m) {
      const float av = ac[(size_t)m * COLS];
      acc0 = fmaf(a0[m], av, acc0);
      acc1 = fmaf(a1[m], av, acc1);
      acc2 = fmaf(a2[m], av, acc2);
      acc3 = fmaf(a3[m], av, acc3);
    }

    out_pred[(size_t)(k0 + 0) * COLS + col] =
        acc0 * ws_ss[(size_t)(k0 + 0) * COLS + col];
    out_pred[(size_t)(k0 + 1) * COLS + col] =
        acc1 * ws_ss[(size_t)(k0 + 1) * COLS + col];
    out_pred[(size_t)(k0 + 2) * COLS + col] =
        acc2 * ws_ss[(size_t)(k0 + 2) * COLS + col];
    out_pred[(size_t)(k0 + 3) * COLS + col] =
        acc3 * ws_ss[(size_t)(k0 + 3) * COLS + col];
  }
}

extern "C" void kernel_launch(void* const* d_in, const int* in_sizes, int n_in,
                              void* d_out, int out_size, void* d_ws,
                              size_t ws_size, hipStream_t stream) {
  const float* x = (const float*)d_in[0];     // (128,2,1024)
  const float* Amat = (const float*)d_in[1];  // (128,128)
  const float* taus = (const float*)d_in[2];  // (128,2)
  const float* r0d = (const float*)d_in[3];   // (128,2)

  float* out = (float*)d_out;
  float* out_pred = out;             // (128,2,1024)
  float* out_signal = out + NHL;     // (128,2,1024)
  float* out_tmatT = out + 2 * NHL;  // (128,128) = Amat + I

  float* ws = (float*)d_ws;
  float* ws_alpha = ws;                          // NHL floats
  float* ws_ss = ws + NHL;                       // NHL floats
  unsigned* flags = (unsigned*)(ws + 2 * NHL);   // NH barrier flags

  fused_kernel<<<NH, 256, 0, stream>>>(x, Amat, taus, r0d, out_pred,
                                       out_signal, out_tmatT, ws_alpha, ws_ss,
                                       flags);
}

// Round 3
// 69.745 us; speedup vs baseline: 1.6045x; 1.6045x over previous
//
#include <hip/hip_runtime.h>
#include <hip/hip_bf16.h>

// Problem constants (from reference): N=128 nodes, H=2 heads, L=1024.
#define NN 128
#define HH 2
#define LL 1024
#define NH (NN * HH)          // 256 rows
#define NHL (NN * HH * LL)    // 262144 elements per (n,h,l) tensor
#define COLS (HH * LL)        // 2048 columns of the alpha matrix

// Kernel 1: per-(n,h) row — relu, cumsum (-> Ss), linear decay recurrence
// (-> Is -> alpha). One block of 256 threads per row; each thread owns 4
// consecutive elements. Wave-level shuffle scans (no barrier) + one LDS
// exchange of the 4 wave totals (1 barrier). Recurrence Is[i] = d*Is[i-1] +
// s[i] with uniform per-row ratio: chunk ratio D = d^4, wave ratio W = D^64.
__global__ __launch_bounds__(256) void row_scan_kernel(
    const float* __restrict__ x, const float* __restrict__ taus,
    const float* __restrict__ r0d, float* __restrict__ out_signal,
    float* __restrict__ ws_alpha, float* __restrict__ ws_ss) {
  const int row = blockIdx.x;   // n*H + h
  const int tid = threadIdx.x;  // 0..255
  const int lane = tid & 63;
  const int wave = tid >> 6;

  const float4* xr = (const float4*)(x + (size_t)row * LL);
  float4 v = xr[tid];
  float s0 = fmaxf(v.x, 0.f);
  float s1 = fmaxf(v.y, 0.f);
  float s2 = fmaxf(v.z, 0.f);
  float s3 = fmaxf(v.w, 0.f);

  const float tau = taus[row];
  const float d = 1.f - 1.f / tau;  // == exp(log(1 - 1/tau))
  const float R0 = r0d[row];

  // thread-local inclusive prefix sums (chunk of 4)
  float c0 = s0, c1 = c0 + s1, c2 = c1 + s2, c3 = c2 + s3;
  // thread-local decay recurrence (zero incoming state)
  float l0 = s0;
  float l1 = fmaf(d, l0, s1);
  float l2 = fmaf(d, l1, s2);
  float l3 = fmaf(d, l2, s3);

  // in-wave weighted inclusive scan over (chunk sum, chunk-end state)
  float vs = c3;
  float vi = l3;
  float D = d * d;
  D = D * D;     // d^4
  float Dp = D;  // D^off
#pragma unroll
  for (int off = 1; off < 64; off <<= 1) {
    float ps = __shfl_up(vs, off);
    float pi = __shfl_up(vi, off);
    if (lane >= off) {
      vs += ps;
      vi = fmaf(Dp, pi, vi);
    }
    Dp *= Dp;
  }
  // Dp == D^64 == wave ratio W

  __shared__ float tw_s[4];
  __shared__ float tw_i[4];
  if (lane == 63) {
    tw_s[wave] = vs;
    tw_i[wave] = vi;
  }
  __syncthreads();

  // wave-incoming totals (sequential combine over earlier waves)
  float S_in = 0.f, I_in = 0.f;
  for (int u = 0; u < wave; ++u) {
    S_in += tw_s[u];
    I_in = fmaf(I_in, Dp, tw_i[u]);  // I = I*W + I_u
  }

  // per-lane exclusive (state at end of previous chunk, within wave)
  float es = __shfl_up(vs, 1);
  float ei = __shfl_up(vi, 1);
  if (lane == 0) {
    es = 0.f;
    ei = 0.f;
  }
  const float exs = S_in + es;
  // wave-incoming state decays D^lane before reaching this chunk (D>0 = d^4)
  const float state = fmaf(I_in, exp2f((float)lane * log2f(D)), ei);

  // finalize per element
  float cum0 = exs + c0, cum1 = exs + c1, cum2 = exs + c2, cum3 = exs + c3;
  float is0 = fmaf(d, state, s0);
  float is1 = fmaf(d, is0, s1);
  float is2 = fmaf(d, is1, s2);
  float is3 = fmaf(d, is2, s3);

  float4 sig = make_float4(s0, s1, s2, s3);
  float4 ss = make_float4(1.f - cum0, 1.f - cum1, 1.f - cum2, 1.f - cum3);
  float4 al = make_float4(1.f - __expf(-R0 * is0), 1.f - __expf(-R0 * is1),
                          1.f - __expf(-R0 * is2), 1.f - __expf(-R0 * is3));

  const size_t base = (size_t)row * LL / 4 + tid;
  ((float4*)(out_signal))[base] = sig;  // output 1: signal
  ((float4*)(ws_alpha))[base] = al;
  ((float4*)(ws_ss))[base] = ss;
}

// Kernel 2: Alpha[k,col] = alpha[k,col] + sum_m Amat[k,m]*alpha[m,col];
// predSignal = Alpha * Ss. k-tiled by 4. Latency-bound on the 128 strided
// alpha loads (8KB stride -> one fresh L2 line each, ~200cyc). This round:
// unroll 16 (16 outstanding loads, was 8) and hoist the 4 ws_ss loads above
// the loop so their latency hides under the m-loop instead of sitting
// exposed at the tail.
__global__ __launch_bounds__(256) void mix_kernel(
    const float* __restrict__ Amat, const float* __restrict__ ws_alpha,
    const float* __restrict__ ws_ss, float* __restrict__ pred,
    float* __restrict__ tmatT) {
  const int bid = blockIdx.x;  // 0..255
  const int tid = threadIdx.x;
  const int rg = bid >> 3;                                 // 32 rowgroups
  const int cg = bid & 7;                                  // 8 colgroups
  const int col = (cg << 8) + tid;                         // 0..2047
  const int k0 = __builtin_amdgcn_readfirstlane(rg << 2);  // block-uniform

  const float* __restrict__ a0 = Amat + (k0 + 0) * NN;
  const float* __restrict__ a1 = Amat + (k0 + 1) * NN;
  const float* __restrict__ a2 = Amat + (k0 + 2) * NN;
  const float* __restrict__ a3 = Amat + (k0 + 3) * NN;

  // +I term (issue first: independent loads)
  float acc0 = ws_alpha[(size_t)(k0 + 0) * COLS + col];
  float acc1 = ws_alpha[(size_t)(k0 + 1) * COLS + col];
  float acc2 = ws_alpha[(size_t)(k0 + 2) * COLS + col];
  float acc3 = ws_alpha[(size_t)(k0 + 3) * COLS + col];

  // hoisted Ss loads: latency hides under the m-loop
  const float ss0 = ws_ss[(size_t)(k0 + 0) * COLS + col];
  const float ss1 = ws_ss[(size_t)(k0 + 1) * COLS + col];
  const float ss2 = ws_ss[(size_t)(k0 + 2) * COLS + col];
  const float ss3 = ws_ss[(size_t)(k0 + 3) * COLS + col];

  const float* __restrict__ ac = ws_alpha + col;
#pragma unroll 16
  for (int m = 0; m < NN; ++m) {
    const float av = ac[(size_t)m * COLS];
    acc0 = fmaf(a0[m], av, acc0);
    acc1 = fmaf(a1[m], av, acc1);
    acc2 = fmaf(a2[m], av, acc2);
    acc3 = fmaf(a3[m], av, acc3);
  }

  pred[(size_t)(k0 + 0) * COLS + col] = acc0 * ss0;
  pred[(size_t)(k0 + 1) * COLS + col] = acc1 * ss1;
  pred[(size_t)(k0 + 2) * COLS + col] = acc2 * ss2;
  pred[(size_t)(k0 + 3) * COLS + col] = acc3 * ss3;

  // tmatT = Amat + I (16384 elements, first 4096 flat threads, float4 each)
  const int fid = bid * 256 + tid;
  if (fid < NN * NN / 4) {
    float4 t = ((const float4*)Amat)[fid];
    const int e = fid << 2;
    if (((e + 0) % (NN + 1)) == 0) t.x += 1.f;
    if (((e + 1) % (NN + 1)) == 0) t.y += 1.f;
    if (((e + 2) % (NN + 1)) == 0) t.z += 1.f;
    if (((e + 3) % (NN + 1)) == 0) t.w += 1.f;
    ((float4*)tmatT)[fid] = t;
  }
}

extern "C" void kernel_launch(void* const* d_in, const int* in_sizes, int n_in,
                              void* d_out, int out_size, void* d_ws,
                              size_t ws_size, hipStream_t stream) {
  const float* x = (const float*)d_in[0];     // (128,2,1024)
  const float* Amat = (const float*)d_in[1];  // (128,128)
  const float* taus = (const float*)d_in[2];  // (128,2)
  const float* r0d = (const float*)d_in[3];   // (128,2)

  float* out = (float*)d_out;
  float* out_pred = out;             // (128,2,1024)
  float* out_signal = out + NHL;     // (128,2,1024)
  float* out_tmatT = out + 2 * NHL;  // (128,128) = Amat + I

  float* ws = (float*)d_ws;
  float* ws_alpha = ws;     // NHL floats
  float* ws_ss = ws + NHL;  // NHL floats

  row_scan_kernel<<<NH, 256, 0, stream>>>(x, taus, r0d, out_signal, ws_alpha,
                                          ws_ss);
  mix_kernel<<<256, 256, 0, stream>>>(Amat, ws_alpha, ws_ss, out_pred,
                                      out_tmatT);
}

// Round 4
// 67.196 us; speedup vs baseline: 1.6654x; 1.0379x over previous
//
#include <hip/hip_runtime.h>
#include <hip/hip_bf16.h>

// Problem constants (from reference): N=128 nodes, H=2 heads, L=1024.
#define NN 128
#define HH 2
#define LL 1024
#define NH (NN * HH)          // 256 rows
#define NHL (NN * HH * LL)    // 262144 elements per (n,h,l) tensor
#define COLS (HH * LL)        // 2048 columns of the alpha matrix

// Kernel 1: per-(n,h) row — relu, cumsum (-> Ss), linear decay recurrence
// (-> Is -> alpha). One block of 256 threads per row; each thread owns 4
// consecutive elements. Wave-level shuffle scans (no barrier) + one LDS
// exchange of the 4 wave totals (1 barrier). Recurrence Is[i] = d*Is[i-1] +
// s[i] with uniform per-row ratio: chunk ratio D = d^4, wave ratio W = D^64.
// This round: also emits tmatT (= Amat + I) from blocks 0..15, taking that
// work off mix_kernel's critical path (it only reads Amat).
__global__ __launch_bounds__(256) void row_scan_kernel(
    const float* __restrict__ x, const float* __restrict__ taus,
    const float* __restrict__ r0d, const float* __restrict__ Amat,
    float* __restrict__ out_signal, float* __restrict__ tmatT,
    float* __restrict__ ws_alpha, float* __restrict__ ws_ss) {
  const int row = blockIdx.x;   // n*H + h
  const int tid = threadIdx.x;  // 0..255
  const int lane = tid & 63;
  const int wave = tid >> 6;

  const float4* xr = (const float4*)(x + (size_t)row * LL);
  float4 v = xr[tid];
  float s0 = fmaxf(v.x, 0.f);
  float s1 = fmaxf(v.y, 0.f);
  float s2 = fmaxf(v.z, 0.f);
  float s3 = fmaxf(v.w, 0.f);

  // tmatT = Amat + I (16384 elements; blocks 0..15, one float4 per thread).
  if (row < 16) {
    const int fid = row * 256 + tid;  // 4096 float4s total
    float4 t = ((const float4*)Amat)[fid];
    const int e = fid << 2;
    if (((e + 0) % (NN + 1)) == 0) t.x += 1.f;
    if (((e + 1) % (NN + 1)) == 0) t.y += 1.f;
    if (((e + 2) % (NN + 1)) == 0) t.z += 1.f;
    if (((e + 3) % (NN + 1)) == 0) t.w += 1.f;
    ((float4*)tmatT)[fid] = t;
  }

  const float tau = taus[row];
  const float d = 1.f - 1.f / tau;  // == exp(log(1 - 1/tau))
  const float R0 = r0d[row];

  // thread-local inclusive prefix sums (chunk of 4)
  float c0 = s0, c1 = c0 + s1, c2 = c1 + s2, c3 = c2 + s3;
  // thread-local decay recurrence (zero incoming state)
  float l0 = s0;
  float l1 = fmaf(d, l0, s1);
  float l2 = fmaf(d, l1, s2);
  float l3 = fmaf(d, l2, s3);

  // in-wave weighted inclusive scan over (chunk sum, chunk-end state)
  float vs = c3;
  float vi = l3;
  float D = d * d;
  D = D * D;     // d^4
  float Dp = D;  // D^off
#pragma unroll
  for (int off = 1; off < 64; off <<= 1) {
    float ps = __shfl_up(vs, off);
    float pi = __shfl_up(vi, off);
    if (lane >= off) {
      vs += ps;
      vi = fmaf(Dp, pi, vi);
    }
    Dp *= Dp;
  }
  // Dp == D^64 == wave ratio W

  __shared__ float tw_s[4];
  __shared__ float tw_i[4];
  if (lane == 63) {
    tw_s[wave] = vs;
    tw_i[wave] = vi;
  }
  __syncthreads();

  // wave-incoming totals (sequential combine over earlier waves)
  float S_in = 0.f, I_in = 0.f;
  for (int u = 0; u < wave; ++u) {
    S_in += tw_s[u];
    I_in = fmaf(I_in, Dp, tw_i[u]);  // I = I*W + I_u
  }

  // per-lane exclusive (state at end of previous chunk, within wave)
  float es = __shfl_up(vs, 1);
  float ei = __shfl_up(vi, 1);
  if (lane == 0) {
    es = 0.f;
    ei = 0.f;
  }
  const float exs = S_in + es;
  // wave-incoming state decays D^lane before reaching this chunk (D>0 = d^4)
  const float state = fmaf(I_in, exp2f((float)lane * log2f(D)), ei);

  // finalize per element
  float cum0 = exs + c0, cum1 = exs + c1, cum2 = exs + c2, cum3 = exs + c3;
  float is0 = fmaf(d, state, s0);
  float is1 = fmaf(d, is0, s1);
  float is2 = fmaf(d, is1, s2);
  float is3 = fmaf(d, is2, s3);

  float4 sig = make_float4(s0, s1, s2, s3);
  float4 ss = make_float4(1.f - cum0, 1.f - cum1, 1.f - cum2, 1.f - cum3);
  float4 al = make_float4(1.f - __expf(-R0 * is0), 1.f - __expf(-R0 * is1),
                          1.f - __expf(-R0 * is2), 1.f - __expf(-R0 * is3));

  const size_t base = (size_t)row * LL / 4 + tid;
  ((float4*)(out_signal))[base] = sig;  // output 1: signal
  ((float4*)(ws_alpha))[base] = al;
  ((float4*)(ws_ss))[base] = ss;
}

// Kernel 2: Alpha[k,col] = alpha[k,col] + sum_m Amat[k,m]*alpha[m,col];
// predSignal = Alpha * Ss. This round: k-tile 2 (was 4) -> 512 blocks ->
// 2 blocks/CU = 8 waves/CU. The m-loop's 128 L2-strided loads (~200-300cyc
// each, 8KB stride) are latency-exposed at 4 waves/CU (VALUBusy ~2% in the
// round-1 fused profile); doubling TLP is the remaining lever after ILP
// tuning (round 3) came back neutral. L2 re-read grows 33->66 MB, still
// ~1us at the 34.5 TB/s L2 ceiling.
__global__ __launch_bounds__(256) void mix_kernel(
    const float* __restrict__ Amat, const float* __restrict__ ws_alpha,
    const float* __restrict__ ws_ss, float* __restrict__ pred) {
  const int bid = blockIdx.x;  // 0..511
  const int tid = threadIdx.x;
  const int rg = bid >> 3;                                 // 64 rowgroups
  const int cg = bid & 7;                                  // 8 colgroups
  const int col = (cg << 8) + tid;                         // 0..2047
  const int k0 = __builtin_amdgcn_readfirstlane(rg << 1);  // block-uniform

  const float* __restrict__ a0 = Amat + (k0 + 0) * NN;
  const float* __restrict__ a1 = Amat + (k0 + 1) * NN;

  // +I term (issue first: independent loads)
  float acc0 = ws_alpha[(size_t)(k0 + 0) * COLS + col];
  float acc1 = ws_alpha[(size_t)(k0 + 1) * COLS + col];

  // hoisted Ss loads: latency hides under the m-loop
  const float ss0 = ws_ss[(size_t)(k0 + 0) * COLS + col];
  const float ss1 = ws_ss[(size_t)(k0 + 1) * COLS + col];

  const float* __restrict__ ac = ws_alpha + col;
#pragma unroll 8
  for (int m = 0; m < NN; ++m) {
    const float av = ac[(size_t)m * COLS];
    acc0 = fmaf(a0[m], av, acc0);
    acc1 = fmaf(a1[m], av, acc1);
  }

  pred[(size_t)(k0 + 0) * COLS + col] = acc0 * ss0;
  pred[(size_t)(k0 + 1) * COLS + col] = acc1 * ss1;
}

extern "C" void kernel_launch(void* const* d_in, const int* in_sizes, int n_in,
                              void* d_out, int out_size, void* d_ws,
                              size_t ws_size, hipStream_t stream) {
  const float* x = (const float*)d_in[0];     // (128,2,1024)
  const float* Amat = (const float*)d_in[1];  // (128,128)
  const float* taus = (const float*)d_in[2];  // (128,2)
  const float* r0d = (const float*)d_in[3];   // (128,2)

  float* out = (float*)d_out;
  float* out_pred = out;             // (128,2,1024)
  float* out_signal = out + NHL;     // (128,2,1024)
  float* out_tmatT = out + 2 * NHL;  // (128,128) = Amat + I

  float* ws = (float*)d_ws;
  float* ws_alpha = ws;     // NHL floats
  float* ws_ss = ws + NHL;  // NHL floats

  row_scan_kernel<<<NH, 256, 0, stream>>>(x, taus, r0d, Amat, out_signal,
                                          out_tmatT, ws_alpha, ws_ss);
  mix_kernel<<<512, 256, 0, stream>>>(Amat, ws_alpha, ws_ss, out_pred);
}